// Round 10
// baseline (368.647 us; speedup 1.0000x reference)
//
#include <hip/hip_runtime.h>
#include <hip/hip_bf16.h>

// Sizes fixed by the reference problem.
#define CN 32
#define RN 256
#define DN 512
#define NN 32
#define LN 256

// LDS layout of main kernel (bytes):
//  sAt   : bf16 [256][256] = 131072, 16B-chunk XOR swizzle (chunk ^= r&7)
//  stage : 32768 single-buffered staging:
//            phase A: conS @ +0 (16K), lawsS @ +16384 (16K)
//            phase B: Gs   @ +0 (16K)
//          Overlays (barrier-ordered into dead regions):
//            ssP  @ +0     [256][4] f32   denP @ +4096 [256][4] f32
//            red  @ +8192  [4] f32        w12P @ +16384 [256][4] f32
//            nsqP @ +0     [256][4] f32 (after phase-B k-loop + barrier)
//  total : 163840 = 160 KiB (1 block/CU, 16 waves, 4 waves/SIMD)
#define STAGE_OFF 131072
#define SMEM_TOTAL 163840

typedef short v8s __attribute__((ext_vector_type(8)));
typedef float v4f __attribute__((ext_vector_type(4)));
typedef const __attribute__((address_space(1))) void* gas1_t;
typedef __attribute__((address_space(3))) void* las3_t;

__device__ __forceinline__ void gl2lds16(const void* g, void* l) {
  __builtin_amdgcn_global_load_lds((gas1_t)g, (las3_t)l, 16, 0, 0);
}

__device__ __forceinline__ unsigned short f2bf(float x) {
  unsigned int u = __float_as_uint(x);
  u = (u + 0x7fffu + ((u >> 16) & 1u)) >> 16;  // RNE
  return (unsigned short)u;
}
__device__ __forceinline__ float bf2f(unsigned short h) {
  return __uint_as_float(((unsigned int)h) << 16);
}

// Staging buffers ([256][32] shorts): 16B chunks XOR-swizzled with (r>>1)&3.
// Writes absorb the swizzle in the global fetch column; reads via this helper.
__device__ __forceinline__ const v8s* stgFrag(const unsigned short* buf, int r,
                                              int quad) {
  return (const v8s*)(buf + r * 32 + ((quad ^ ((r >> 1) & 3)) << 3));
}

// sAt addressing: row-major stride 256 shorts, 16B chunks XOR-swizzled by row.
__device__ __forceinline__ int satIdx(int r, int col) {
  return (r << 8) | ((((col >> 3) ^ (r & 7)) << 3) | (col & 7));
}

// ---------------------------------------------------------------------------
// Prep: fp32 -> bf16 copies of laws & contracts, plus ||contracts[c,r,:]||.
// ---------------------------------------------------------------------------
__global__ __launch_bounds__(256) void prep_kernel(
    const float* __restrict__ con, const float* __restrict__ laws,
    unsigned short* __restrict__ lawsB, unsigned short* __restrict__ conB,
    float* __restrict__ cnorm) {
  const int bid = blockIdx.x;
  const int t = threadIdx.x;
  if (bid < 2048) {
    const int r = bid * 4 + (t >> 6);
    const int lane = t & 63;
    const float4* src = (const float4*)(con + r * DN + lane * 8);
    float4 x0 = src[0], x1 = src[1];
    unsigned short h[8];
    h[0] = f2bf(x0.x); h[1] = f2bf(x0.y); h[2] = f2bf(x0.z); h[3] = f2bf(x0.w);
    h[4] = f2bf(x1.x); h[5] = f2bf(x1.y); h[6] = f2bf(x1.z); h[7] = f2bf(x1.w);
    *(v8s*)(conB + r * DN + lane * 8) = *(v8s*)h;
    float s = x0.x * x0.x + x0.y * x0.y + x0.z * x0.z + x0.w * x0.w +
              x1.x * x1.x + x1.y * x1.y + x1.z * x1.z + x1.w * x1.w;
#pragma unroll
    for (int m = 1; m < 64; m <<= 1) s += __shfl_xor(s, m, 64);
    if (lane == 0) cnorm[r] = sqrtf(s);
  } else {
    const int off = (bid - 2048) * 2048 + t * 8;
    const float4* src = (const float4*)(laws + off);
    float4 x0 = src[0], x1 = src[1];
    unsigned short h[8];
    h[0] = f2bf(x0.x); h[1] = f2bf(x0.y); h[2] = f2bf(x0.z); h[3] = f2bf(x0.w);
    h[4] = f2bf(x1.x); h[5] = f2bf(x1.y); h[6] = f2bf(x1.z); h[7] = f2bf(x1.w);
    *(v8s*)(lawsB + off) = *(v8s*)h;
  }
}

// ---------------------------------------------------------------------------
// Gram via MFMA. 256 blocks = (n, 32-row stripe) -> all CUs busy.
// ---------------------------------------------------------------------------
__global__ __launch_bounds__(512) void gramm_kernel(
    const unsigned short* __restrict__ lawsB, unsigned short* __restrict__ G) {
  __shared__ unsigned short slice[256 * 32];  // 16 KB
  const int bx = blockIdx.x;
  const int n = bx >> 3;
  const int m0 = (bx & 7) << 5;
  const int t = threadIdx.x;
  const int lane = t & 63;
  const int w = t >> 6;
  const int quad = lane >> 4;
  const int l16 = lane & 15;
  const int sub = t & 3;
  const int rQ = t >> 2;
  const int subx = sub ^ ((rQ >> 1) & 3);
  const int rg = w >> 2;  // 0..1
  const int cg = w & 3;   // 0..3
  const unsigned short* lawN = lawsB + n * (LN * DN);

  v4f acc[4];
#pragma unroll
  for (int b = 0; b < 4; ++b) acc[b] = (v4f){0.f, 0.f, 0.f, 0.f};

  for (int ch = 0; ch < 16; ++ch) {
    const int dk = ch << 5;
    __syncthreads();
#pragma unroll
    for (int i = 0; i < 2; ++i)
      gl2lds16(lawN + (i * 128 + rQ) * DN + dk + subx * 8,
               (char*)slice + i * 8192 + t * 16);
    __syncthreads();
    v8s af = *stgFrag(slice, m0 + rg * 16 + l16, quad);
#pragma unroll
    for (int ct = 0; ct < 4; ++ct) {
      v8s bf = *stgFrag(slice, cg * 64 + ct * 16 + l16, quad);
      acc[ct] = __builtin_amdgcn_mfma_f32_16x16x32_bf16(af, bf, acc[ct], 0, 0, 0);
    }
  }
  unsigned short* g = G + n * (LN * LN);
#pragma unroll
  for (int ct = 0; ct < 4; ++ct)
#pragma unroll
    for (int reg = 0; reg < 4; ++reg) {
      const int l = m0 + rg * 16 + quad * 4 + reg;
      g[l * LN + cg * 64 + ct * 16 + l16] = f2bf(acc[ct][reg]);
    }
}

// ---------------------------------------------------------------------------
// Main: one block per (n,c), 1024 threads = 16 waves = 4x4 grid of 64x64
// wave tiles (acc[4][4] = 64 AGPR; ~55 VGPR -> fits the 128-reg budget of
// 4 waves/SIMD with NO spills -- R8's spill sources removed: A-operand now
// staged in LDS (no af[4] global live range), single-buffered staging (no
// dbuf/prefetch state). Square tiles halve per-CU LDS read traffic vs the
// 32x256 layout (128KB vs 144-272KB per chunk) -- the R2..R9 limiter.
// ---------------------------------------------------------------------------
__global__ __launch_bounds__(1024, 4) void main_kernel(
    const int* __restrict__ law_lens, const unsigned short* __restrict__ lawsB,
    const unsigned short* __restrict__ conB, const unsigned short* __restrict__ Gm,
    const float* __restrict__ cnorm, float* __restrict__ out) {
  extern __shared__ char smem[];
  unsigned short* sAt = (unsigned short*)smem;  // [256][256] swizzled
  char* stage = smem + STAGE_OFF;

  const int bid = blockIdx.x;
  const int n = bid >> 5;  // 32 consecutive blocks share one n
  const int c = bid & 31;
  const int t = threadIdx.x;
  const int lane = t & 63;
  const int w = t >> 6;  // wave 0..15
  const int quad = lane >> 4;
  const int l16 = lane & 15;
  const int sub = t & 3;
  const int rQ = t >> 2;                   // 0..255
  const int subx = sub ^ ((rQ >> 1) & 3);  // swizzled source chunk
  const int rg = w >> 2;                   // row-group: laws rows rg*64..+63
  const int cg = w & 3;                    // col-group: con rows cg*64..+63
  const int rbase = rg << 6;
  const int cbase = cg << 6;
  const int len = law_lens[n];
  const int nCh = (len + 31) >> 5;  // phase-B k-chunks (block-uniform)
  const float kInv = 0.04419417382415922f;  // 1/sqrt(512)

  const unsigned short* lawN = lawsB + n * (LN * DN);
  const unsigned short* conC = conB + c * (RN * DN);
  const unsigned short* Gn = Gm + n * (LN * LN);

  unsigned short* conS = (unsigned short*)stage;
  unsigned short* lawsS = (unsigned short*)(stage + 16384);
  float* ssP = (float*)stage;             // [256][4]
  float* denP = (float*)(stage + 4096);   // [256][4]
  float* red = (float*)(stage + 8192);    // [4]
  float* w12P = (float*)(stage + 16384);  // [256][4]
  float* nsqP = (float*)stage;            // [256][4] (phase-B epilogue)

  // ---------------- Phase A: S = laws @ con^T ----------------
  v4f acc[4][4];  // [rt = l-tile][ct = r-tile]
#pragma unroll
  for (int a = 0; a < 4; ++a)
#pragma unroll
    for (int b = 0; b < 4; ++b) acc[a][b] = (v4f){0.f, 0.f, 0.f, 0.f};

  for (int ch = 0; ch < 16; ++ch) {
    const int dk = ch << 5;
    __syncthreads();  // staging buffer free (prev chunk's readers done)
    gl2lds16(conC + rQ * DN + dk + subx * 8, stage + t * 16);
    gl2lds16(lawN + rQ * DN + dk + subx * 8, stage + 16384 + t * 16);
    __syncthreads();  // drain vmcnt for global_load_lds
    v8s bfv[4];
#pragma unroll
    for (int ct = 0; ct < 4; ++ct)
      bfv[ct] = *stgFrag(conS, cbase + ct * 16 + l16, quad);
#pragma unroll
    for (int rt = 0; rt < 4; ++rt) {
      v8s af = *stgFrag(lawsS, rbase + rt * 16 + l16, quad);
#pragma unroll
      for (int ct = 0; ct < 4; ++ct)
        acc[rt][ct] = __builtin_amdgcn_mfma_f32_16x16x32_bf16(af, bfv[ct], acc[rt][ct], 0, 0, 0);
    }
  }
  __syncthreads();  // all staged reads done; stage region reusable (ssP)

  // Softmax pass 1: per-row ss partials over this wave's 64 r-cols.
#pragma unroll
  for (int rt = 0; rt < 4; ++rt)
#pragma unroll
    for (int reg = 0; reg < 4; ++reg) {
      float ssp = 0.f;
#pragma unroll
      for (int ct = 0; ct < 4; ++ct) {
        const float v = acc[rt][ct][reg] * kInv;
        const float lv = v > 0.f ? v : 0.1f * v;
        ssp += lv * lv;
      }
#pragma unroll
      for (int m = 1; m < 16; m <<= 1) ssp += __shfl_xor(ssp, m, 64);
      if (l16 == 0) ssP[(rbase + rt * 16 + quad * 4 + reg) * 4 + cg] = ssp;
    }
  __syncthreads();

  // Pass 2: den partials (|lv*inv| <= 1 -> exp in [1/e, e], no max needed).
#pragma unroll
  for (int rt = 0; rt < 4; ++rt)
#pragma unroll
    for (int reg = 0; reg < 4; ++reg) {
      const int row = rbase + rt * 16 + quad * 4 + reg;
      const float4 s4 = *(const float4*)&ssP[row * 4];
      const float inv = 1.f / (sqrtf(s4.x + s4.y + s4.z + s4.w) + 1e-8f);
      float dnp = 0.f;
#pragma unroll
      for (int ct = 0; ct < 4; ++ct) {
        const float v = acc[rt][ct][reg] * kInv;
        const float lv = v > 0.f ? v : 0.1f * v;
        dnp += __expf(lv * inv);
      }
#pragma unroll
      for (int m = 1; m < 16; m <<= 1) dnp += __shfl_xor(dnp, m, 64);
      if (l16 == 0) denP[row * 4 + cg] = dnp;
    }
  __syncthreads();

  // Pass 3: emit attn -> sAt (packed b64), accumulate w12 per r-col.
  float w12c[4] = {0.f, 0.f, 0.f, 0.f};
#pragma unroll
  for (int rt = 0; rt < 4; ++rt) {
    const int row0 = rbase + rt * 16 + quad * 4;
    float invv[4], scv[4];
#pragma unroll
    for (int reg = 0; reg < 4; ++reg) {
      const float4 s4 = *(const float4*)&ssP[(row0 + reg) * 4];
      invv[reg] = 1.f / (sqrtf(s4.x + s4.y + s4.z + s4.w) + 1e-8f);
      const float4 d4 = *(const float4*)&denP[(row0 + reg) * 4];
      scv[reg] = (row0 + reg < len) ? 4.f / (d4.x + d4.y + d4.z + d4.w) : 0.f;
    }
#pragma unroll
    for (int ct = 0; ct < 4; ++ct) {
      unsigned int p0 = 0, p1 = 0;
#pragma unroll
      for (int reg = 0; reg < 4; ++reg) {
        const float v = acc[rt][ct][reg] * kInv;
        const float lv = v > 0.f ? v : 0.1f * v;
        const float a = __expf(lv * invv[reg]) * scv[reg];
        w12c[ct] += a * v;  // raw S -> cosine numerator (fp32 exact)
        const unsigned int h = f2bf(a);
        if (reg == 0) p0 = h;
        else if (reg == 1) p0 |= h << 16;
        else if (reg == 2) p1 = h;
        else p1 |= h << 16;
      }
      uint2 pk; pk.x = p0; pk.y = p1;
      *(uint2*)(sAt + satIdx(cbase + ct * 16 + l16, row0)) = pk;
    }
  }
  // w12: sum across quads (l within wave), publish per (r-col, row-group).
#pragma unroll
  for (int ct = 0; ct < 4; ++ct) {
    w12c[ct] += __shfl_xor(w12c[ct], 16, 64);
    w12c[ct] += __shfl_xor(w12c[ct], 32, 64);
  }
  if (quad == 0) {
#pragma unroll
    for (int ct = 0; ct < 4; ++ct)
      w12P[(cbase + ct * 16 + l16) * 4 + rg] = w12c[ct];
  }
  __syncthreads();  // sAt + w12P ready; ssP/denP dead

  float w12f = 0.f;
  if (t < 256) {
    const float4 q = *(const float4*)&w12P[t * 4];
    w12f = q.x + q.y + q.z + q.w;  // held in a register through phase B
  }

  // ---------------- Phase B: U = At @ G (k capped at ceil(len/32)) --------
  v4f accB[4][4];  // [rt = r-tile][ct = l'-tile]
#pragma unroll
  for (int a = 0; a < 4; ++a)
#pragma unroll
    for (int b = 0; b < 4; ++b) accB[a][b] = (v4f){0.f, 0.f, 0.f, 0.f};

  for (int ch = 0; ch < nCh; ++ch) {
    const int lk = ch << 5;
    __syncthreads();  // also orders w12P reads / pass-3 before Gs overwrite
    gl2lds16(Gn + rQ * LN + lk + subx * 8, stage + t * 16);
    __syncthreads();
    v8s afv[4];
#pragma unroll
    for (int rt = 0; rt < 4; ++rt)
      afv[rt] = *(const v8s*)(sAt + satIdx(rbase + rt * 16 + l16, lk + quad * 8));
#pragma unroll
    for (int ct = 0; ct < 4; ++ct) {
      v8s bf = *stgFrag(conS /*=Gs*/, cbase + ct * 16 + l16, quad);
#pragma unroll
      for (int rt = 0; rt < 4; ++rt)
        accB[rt][ct] = __builtin_amdgcn_mfma_f32_16x16x32_bf16(afv[rt], bf, accB[rt][ct], 0, 0, 0);
    }
  }
  __syncthreads();  // Gs reads done; stage reusable (nsqP)

  // nsq partials: sum_{l'} At[r,l'] U[r,l'] over this wave's 64 l'.
#pragma unroll
  for (int rt = 0; rt < 4; ++rt)
#pragma unroll
    for (int reg = 0; reg < 4; ++reg) {
      const int row = rbase + rt * 16 + quad * 4 + reg;
      float s = 0.f;
#pragma unroll
      for (int ct = 0; ct < 4; ++ct)
        s += accB[rt][ct][reg] * bf2f(sAt[satIdx(row, cbase + ct * 16 + l16)]);
#pragma unroll
      for (int m = 1; m < 16; m <<= 1) s += __shfl_xor(s, m, 64);
      if (l16 == 0) nsqP[row * 4 + cg] = s;
    }
  __syncthreads();

  // ---------------- Phase C ----------------
  float p = 0.f;
  if (t < 256) {
    const float4 q = *(const float4*)&nsqP[t * 4];
    const float nsq = q.x + q.y + q.z + q.w;
    const float w1 = cnorm[c * RN + t];
    const float w2 = sqrtf(fmaxf(nsq, 0.f));
    const float sim = (w12f * 22.627416997969522f) / fmaxf(w1 * w2, 1e-8f);
    p = __expf(6.f * sim);
  }
#pragma unroll
  for (int m = 1; m < 64; m <<= 1) p += __shfl_xor(p, m, 64);
  if (t < 256 && lane == 0) red[w] = p;
  __syncthreads();
  if (t == 0) out[c * NN + n] = logf(red[0] + red[1] + red[2] + red[3]) / 6.f;
}

// ---------------------------------------------------------------------------
extern "C" void kernel_launch(void* const* d_in, const int* in_sizes, int n_in,
                              void* d_out, int out_size, void* d_ws, size_t ws_size,
                              hipStream_t stream) {
  (void)in_sizes; (void)n_in; (void)out_size;
  const float* contracts = (const float*)d_in[0];
  const float* laws = (const float*)d_in[1];
  const int* law_lens = (const int*)d_in[2];
  float* out = (float*)d_out;

  // Workspace layout (21,004,288 B total)
  unsigned short* lawsB = (unsigned short*)d_ws;  // 8 MiB
  unsigned short* conB = lawsB + NN * LN * DN;    // 8 MiB
  unsigned short* G = conB + CN * RN * DN;        // 4 MiB
  float* cnorm = (float*)(G + NN * LN * LN);      // 32 KiB
  if (ws_size < (size_t)21004288) return;

  hipFuncSetAttribute((const void*)main_kernel,
                      hipFuncAttributeMaxDynamicSharedMemorySize, SMEM_TOTAL);

  prep_kernel<<<4096, 256, 0, stream>>>(contracts, laws, lawsB, conB, cnorm);
  gramm_kernel<<<256, 512, 0, stream>>>(lawsB, G);
  main_kernel<<<1024, 1024, SMEM_TOTAL, stream>>>(law_lens, lawsB, conB, G,
                                                  cnorm, out);
}